// Round 15
// baseline (50.596 us; speedup 1.0000x reference)
//
#include <hip/hip_runtime.h>
#include <math.h>

#define NBINS 513
#define NROWS 4000
#define BATCH 8
#define FPW   8                          // output rows per wave
#define ITERS 4                          // 2 independent frames per iteration
#define CHAINS_PER_BATCH (NROWS / FPW)   // 500

typedef const __attribute__((address_space(1))) void* gvp;
typedef __attribute__((address_space(3))) void* lvp;

__device__ __forceinline__ void cmul(float& ar, float& ai, float br, float bi) {
    const float t = ar * br - ai * bi;
    ai = ar * bi + ai * br;
    ar = t;
}

// In-place inverse DFT-8 (omega = e^{+2pi i/8}) on 8 complex register values.
__device__ __forceinline__ void idft8(float* xr, float* xi) {
    const float S = 0.70710678118654752440f;
    float er[4], ei[4], orr[4], oi[4];
    #pragma unroll
    for (int j = 0; j < 4; ++j) {
        er[j]  = xr[j] + xr[j+4];  ei[j] = xi[j] + xi[j+4];
        orr[j] = xr[j] - xr[j+4];  oi[j] = xi[j] - xi[j+4];
    }
    const float f1r = S * (orr[1] - oi[1]), f1i = S * (orr[1] + oi[1]);
    const float f2r = -oi[2],               f2i = orr[2];
    const float f3r = S * (-orr[3] - oi[3]), f3i = S * (orr[3] - oi[3]);
    {
        const float eer = er[0]+er[2], eei = ei[0]+ei[2];
        const float eor = er[0]-er[2], eoi = ei[0]-ei[2];
        const float oer = er[1]+er[3], oei = ei[1]+ei[3];
        const float oor = er[1]-er[3], ooi = ei[1]-ei[3];
        xr[0] = eer + oer;  xi[0] = eei + oei;
        xr[2] = eor - ooi;  xi[2] = eoi + oor;
        xr[4] = eer - oer;  xi[4] = eei - oei;
        xr[6] = eor + ooi;  xi[6] = eoi - oor;
    }
    {
        const float eer = orr[0]+f2r, eei = oi[0]+f2i;
        const float eor = orr[0]-f2r, eoi = oi[0]-f2i;
        const float oer = f1r+f3r,    oei = f1i+f3i;
        const float oor = f1r-f3r,    ooi = f1i-f3i;
        xr[1] = eer + oer;  xi[1] = eei + oei;
        xr[3] = eor - ooi;  xi[3] = eoi + oor;
        xr[5] = eer - oer;  xi[5] = eei - oei;
        xr[7] = eor + ooi;  xi[7] = eoi - oor;
    }
}

__global__ __launch_bounds__(64) void istft_kernel(
    const float* __restrict__ re, const float* __restrict__ im,
    float* __restrict__ out)
{
    __shared__ float  st[5][2][516];   // staging rotation: row t0-1+j -> buf j%5
    __shared__ float2 ex2[512];        // shared exchange (same-wave DS order => safe reuse)

    const int u  = threadIdx.x;        // 0..63
    const int b  = blockIdx.y;
    const int t0 = blockIdx.x * FPW;

    const int k1 = u >> 3;
    const int k2 = u & 7;

    // ---- per-thread twiddles (registers) — R11-verified values ----
    const float w0 = 6.283185307179586476925f / 1024.0f;
    const float F  = 4.8828125e-4f;    // 0.5 (harness) * packed-irfft norm

    float2 twn[8];                     // F * i * w1024^(u+64j)  (pack rotation)
    #pragma unroll
    for (int j = 0; j < 8; ++j) {
        float s, c; sincosf(w0 * (float)(u + 64 * j), &s, &c);
        twn[j] = make_float2(-F * s, F * c);
    }
    float2 wA, wB0, wBs;
    {
        float s, c;
        sincosf(w0 * (float)(16 * k1), &s, &c);     wA  = make_float2(c, s);
        sincosf(w0 * (float)(2 * k2 * k1), &s, &c); wB0 = make_float2(c, s);
        sincosf(w0 * (float)(16 * k2), &s, &c);     wBs = make_float2(c, s);
    }
    const float sg = (u & 1) ? -1.0f : 1.0f;   // (-1)^k for k = u+64j

    const float* rebase = re + (size_t)b * NROWS * NBINS;
    const float* imbase = im + (size_t)b * NROWS * NBINS;

    auto stage = [&](int t, int buf) {
        const float* rp = rebase + (size_t)t * NBINS;
        const float* ip = imbase + (size_t)t * NBINS;
        #pragma unroll
        for (int jj = 0; jj < 8; ++jj)
            __builtin_amdgcn_global_load_lds((gvp)(rp + 64 * jj + u),
                                             (lvp)&st[buf][0][64 * jj], 4, 0, 0);
        __builtin_amdgcn_global_load_lds((gvp)(rp + 449 + u),
                                         (lvp)&st[buf][0][449], 4, 0, 0);
        #pragma unroll
        for (int jj = 0; jj < 8; ++jj)
            __builtin_amdgcn_global_load_lds((gvp)(ip + 64 * jj + u),
                                             (lvp)&st[buf][1][64 * jj], 4, 0, 0);
        __builtin_amdgcn_global_load_lds((gvp)(ip + 449 + u),
                                         (lvp)&st[buf][1][449], 4, 0, 0);
    };  // 18 vmcnt entries per row

    // Y = X_cur + sg * X_prev, hermitian-packed into z (R11 pack + linear combine)
    auto pack = [&](int bp, int bc, float* zr8, float* zi8) {
        const float* frp = st[bp][0]; const float* fip = st[bp][1];
        const float* frc = st[bc][0]; const float* fic = st[bc][1];
        #pragma unroll
        for (int j = 0; j < 8; ++j) {
            const int k = u + 64 * j;
            float xr = fmaf(sg, frp[k], frc[k]);
            float xi = fmaf(sg, fip[k], fic[k]);
            float rc = fmaf(sg, frp[512 - k], frc[512 - k]);
            float ic = -fmaf(sg, fip[512 - k], fic[512 - k]);
            if (k == 0) { xi = 0.f; ic = 0.f; }   // pocketfft c2r: Im(bin 0/512) ignored
            const float er0 = xr + rc, ei0 = xi + ic;
            const float hr0 = xr - rc, hi0 = xi - ic;
            zr8[j] = F * er0 + (twn[j].x * hr0 - twn[j].y * hi0);
            zi8[j] = F * ei0 + (twn[j].x * hi0 + twn[j].y * hr0);
        }
    };

    auto fftS1 = [&](float* zr8, float* zi8) {       // stage A + wA twiddles
        idft8(zr8, zi8);
        float tr = wA.x, ti = wA.y;
        #pragma unroll
        for (int m0 = 1; m0 < 8; ++m0) {
            cmul(zr8[m0], zi8[m0], tr, ti);
            cmul(tr, ti, wA.x, wA.y);
        }
    };
    auto x1w = [&](float* zr8, float* zi8) {
        #pragma unroll
        for (int m0 = 0; m0 < 8; ++m0)
            ex2[64 * m0 + 8 * ((k1 ^ m0) & 7) + k2] = make_float2(zr8[m0], zi8[m0]);
    };
    auto x1r = [&](float* zr8, float* zi8) {
        #pragma unroll
        for (int kk = 0; kk < 8; ++kk) {
            const float2 v = ex2[64 * k1 + 8 * ((kk ^ k1) & 7) + k2];
            zr8[kk] = v.x; zi8[kk] = v.y;
        }
    };
    auto fftS2 = [&](float* zr8, float* zi8) {       // stage B + wB twiddles
        idft8(zr8, zi8);
        float tr = wB0.x, ti = wB0.y;
        #pragma unroll
        for (int m1 = 0; m1 < 8; ++m1) {
            cmul(zr8[m1], zi8[m1], tr, ti);
            cmul(tr, ti, wBs.x, wBs.y);
        }
    };
    auto x2w = [&](float* zr8, float* zi8) {
        #pragma unroll
        for (int m1 = 0; m1 < 8; ++m1)
            ex2[64 * k2 + 8 * ((m1 ^ k2) & 7) + k1] = make_float2(zr8[m1], zi8[m1]);
    };
    auto x2r = [&](float* zr8, float* zi8) {
        #pragma unroll
        for (int kk = 0; kk < 8; ++kk) {
            const float2 v = ex2[64 * kk + 8 * ((k1 ^ kk) & 7) + k2];
            zr8[kk] = v.x; zi8[kk] = v.y;
        }
    };

    // ---- prologue: rows t0-1, t0, t0+1 into bufs 0,1,2 ----
    if (t0 == 0) {
        #pragma unroll
        for (int j = 0; j < 8; ++j) { st[0][0][u + 64 * j] = 0.f; st[0][1][u + 64 * j] = 0.f; }
        if (u == 0) { st[0][0][512] = 0.f; st[0][1][512] = 0.f; }
        stage(0, 1); stage(1, 2);
    } else {
        stage(t0 - 1, 0); stage(t0, 1); stage(t0 + 1, 2);
    }
    asm volatile("s_waitcnt vmcnt(0)" ::: "memory");

    for (int i = 0; i < ITERS; ++i) {
        const int tA = t0 + 2 * i, tB = tA + 1;
        // steady-state queue: [stage x2 rows: 36 loads][stores prev iter: 8]
        if (i) { asm volatile("s_waitcnt vmcnt(8)" ::: "memory"); }

        float zAr[8], zAi[8], zBr[8], zBi[8];
        pack((2 * i) % 5,     (2 * i + 1) % 5, zAr, zAi);   // out[tA] = Y(tA, tA-1)
        pack((2 * i + 1) % 5, (2 * i + 2) % 5, zBr, zBi);   // out[tB] = Y(tB, tB-1)

        // prefetch rows tA+2 (j=2i+3) and tA+3 (j=2i+4)  [R14 bug: was tA+3/tA+4]
        if (i < ITERS - 1) {
            stage(tA + 2, (2 * i + 3) % 5);
            stage(tA + 3, (2 * i + 4) % 5);
        }

        // ---- interleaved FFTs: B's VALU covers A's exchange latency & v.v. ----
        fftS1(zAr, zAi);
        x1w(zAr, zAi);
        fftS1(zBr, zBi);
        x1r(zAr, zAi);
        x1w(zBr, zBi);
        fftS2(zAr, zAi);
        x1r(zBr, zBi);
        x2w(zAr, zAi);
        fftS2(zBr, zBi);
        x2r(zAr, zAi);
        x2w(zBr, zBi);
        idft8(zAr, zAi);                    // stage C (A); regs 4..7 DCE'd
        x2r(zBr, zBi);
        {
            float2* orow = (float2*)(out + ((size_t)b * NROWS + (size_t)tA) * 512);
            #pragma unroll
            for (int m = 0; m < 4; ++m)
                orow[u + 64 * m] = make_float2(zAr[m], zAi[m]);
        }
        idft8(zBr, zBi);                    // stage C (B)
        {
            float2* orow = (float2*)(out + ((size_t)b * NROWS + (size_t)tB) * 512);
            #pragma unroll
            for (int m = 0; m < 4; ++m)
                orow[u + 64 * m] = make_float2(zBr[m], zBi[m]);
        }
    }
}

extern "C" void kernel_launch(void* const* d_in, const int* in_sizes, int n_in,
                              void* d_out, int out_size, void* d_ws, size_t ws_size,
                              hipStream_t stream) {
    const float* re = (const float*)d_in[0];
    const float* im = (const float*)d_in[1];
    float* out = (float*)d_out;
    dim3 grid(CHAINS_PER_BATCH, BATCH);
    istft_kernel<<<grid, 64, 0, stream>>>(re, im, out);
}

// Round 16
// 45.815 us; speedup vs baseline: 1.1043x; 1.1043x over previous
//
#include <hip/hip_runtime.h>
#include <math.h>

#define NBINS 513
#define NROWS 4000
#define BATCH 8
#define FPW   8                          // output rows per chain (1 wave = 1 chain)
#define CHAINS_PER_BATCH (NROWS / FPW)   // 500

typedef const __attribute__((address_space(1))) void* gvp;
typedef __attribute__((address_space(3))) void* lvp;

__device__ __forceinline__ void cmul(float& ar, float& ai, float br, float bi) {
    const float t = ar * br - ai * bi;
    ai = ar * bi + ai * br;
    ar = t;
}

// In-place inverse DFT-8 (omega = e^{+2pi i/8}) on 8 complex register values.
__device__ __forceinline__ void idft8(float* xr, float* xi) {
    const float S = 0.70710678118654752440f;
    float er[4], ei[4], orr[4], oi[4];
    #pragma unroll
    for (int j = 0; j < 4; ++j) {
        er[j]  = xr[j] + xr[j+4];  ei[j] = xi[j] + xi[j+4];
        orr[j] = xr[j] - xr[j+4];  oi[j] = xi[j] - xi[j+4];
    }
    const float f1r = S * (orr[1] - oi[1]), f1i = S * (orr[1] + oi[1]);
    const float f2r = -oi[2],               f2i = orr[2];
    const float f3r = S * (-orr[3] - oi[3]), f3i = S * (orr[3] - oi[3]);
    {   // DFT4 (w4 = +i) over evens -> y0,y2,y4,y6
        const float eer = er[0]+er[2], eei = ei[0]+ei[2];
        const float eor = er[0]-er[2], eoi = ei[0]-ei[2];
        const float oer = er[1]+er[3], oei = ei[1]+ei[3];
        const float oor = er[1]-er[3], ooi = ei[1]-ei[3];
        xr[0] = eer + oer;  xi[0] = eei + oei;
        xr[2] = eor - ooi;  xi[2] = eoi + oor;
        xr[4] = eer - oer;  xi[4] = eei - oei;
        xr[6] = eor + ooi;  xi[6] = eoi - oor;
    }
    {   // DFT4 over odds*w8 -> y1,y3,y5,y7
        const float eer = orr[0]+f2r, eei = oi[0]+f2i;
        const float eor = orr[0]-f2r, eoi = oi[0]-f2i;
        const float oer = f1r+f3r,    oei = f1i+f3i;
        const float oor = f1r-f3r,    ooi = f1i-f3i;
        xr[1] = eer + oer;  xi[1] = eei + oei;
        xr[3] = eor - ooi;  xi[3] = eoi + oor;
        xr[5] = eer - oer;  xi[5] = eei - oei;
        xr[7] = eor + ooi;  xi[7] = eoi - oor;
    }
}

__global__ __launch_bounds__(64) void istft_kernel(
    const float* __restrict__ re, const float* __restrict__ im,
    float* __restrict__ out)
{
    // Staging double-buffer ONLY — the exchange overlays the consumed buffer.
    // st[buf] = 2*516*4 = 4128 B >= 4096 B needed by the float2[512] exchange.
    __shared__ float st[2][2][516];

    const int u  = threadIdx.x;        // 0..63
    const int b  = blockIdx.y;
    const int t0 = blockIdx.x * FPW;

    const int k1 = u >> 3;
    const int k2 = u & 7;

    // ---- per-thread twiddles (registers) ----
    const float w0 = 6.283185307179586476925f / 1024.0f;
    const float F  = 4.8828125e-4f;    // 0.5 (harness) * packed-irfft norm

    float2 twn[8];                     // F * i * w1024^(u+64j)  (pack rotation)
    #pragma unroll
    for (int j = 0; j < 8; ++j) {
        float s, c; sincosf(w0 * (float)(u + 64 * j), &s, &c);
        twn[j] = make_float2(-F * s, F * c);
    }
    float2 wA, wB0, wBs;               // stage twiddle recurrence bases
    {
        float s, c;
        sincosf(w0 * (float)(16 * k1), &s, &c);     wA  = make_float2(c, s);
        sincosf(w0 * (float)(2 * k2 * k1), &s, &c); wB0 = make_float2(c, s);
        sincosf(w0 * (float)(16 * k2), &s, &c);     wBs = make_float2(c, s);
    }

    float2 cc[4];                      // OLA carry (registers)
    #pragma unroll
    for (int m = 0; m < 4; ++m) cc[m] = make_float2(0.f, 0.f);

    const float* rebase = re + (size_t)b * NROWS * NBINS;
    const float* imbase = im + (size_t)b * NROWS * NBINS;

    // ---- async staging of one spectrum row into LDS (size=4: alignment-safe) ----
    auto stage = [&](int t, int buf) {
        const float* rp = rebase + (size_t)t * NBINS;
        const float* ip = imbase + (size_t)t * NBINS;
        #pragma unroll
        for (int jj = 0; jj < 8; ++jj)
            __builtin_amdgcn_global_load_lds((gvp)(rp + 64 * jj + u),
                                             (lvp)&st[buf][0][64 * jj], 4, 0, 0);
        __builtin_amdgcn_global_load_lds((gvp)(rp + 449 + u),
                                         (lvp)&st[buf][0][449], 4, 0, 0);
        #pragma unroll
        for (int jj = 0; jj < 8; ++jj)
            __builtin_amdgcn_global_load_lds((gvp)(ip + 64 * jj + u),
                                             (lvp)&st[buf][1][64 * jj], 4, 0, 0);
        __builtin_amdgcn_global_load_lds((gvp)(ip + 449 + u),
                                         (lvp)&st[buf][1][449], 4, 0, 0);
    };  // 18 vmcnt entries per frame

    // ---- prologue: stage the priming frame ----
    if (t0 == 0) {
        #pragma unroll
        for (int j = 0; j < 8; ++j) { st[0][0][u + 64 * j] = 0.f; st[0][1][u + 64 * j] = 0.f; }
        if (u == 0) { st[0][0][512] = 0.f; st[0][1][512] = 0.f; }
    } else {
        stage(t0 - 1, 0);
    }
    asm volatile("s_waitcnt vmcnt(0)" ::: "memory");

    for (int it = 0; it <= FPW; ++it) {
        const int t = t0 - 1 + it;
        const int c = it & 1;

        // ---- wait for frame t's staging: 18 loads must be done.
        // steady-state queue = [stage(t):18][stores(t-1):4] -> vmcnt(4).
        if (it >= 2)      { asm volatile("s_waitcnt vmcnt(4)" ::: "memory"); }
        else if (it == 1) { asm volatile("s_waitcnt vmcnt(0)" ::: "memory"); }

        // ---- pack from staged LDS row: z = F*e + twn*h  (k = u + 64j) ----
        float zr8[8], zi8[8];
        {
            const float* fr = st[c][0];
            const float* fi = st[c][1];
            #pragma unroll
            for (int j = 0; j < 8; ++j) {
                const int k = u + 64 * j;
                float xr = fr[k], xi = fi[k];
                float rc = fr[512 - k], ic = -fi[512 - k];
                if (k == 0) { xi = 0.f; ic = 0.f; }   // pocketfft c2r: Im ignored
                const float er0 = xr + rc, ei0 = xi + ic;
                const float hr0 = xr - rc, hi0 = xi - ic;
                zr8[j] = F * er0 + (twn[j].x * hr0 - twn[j].y * hi0);
                zi8[j] = F * ei0 + (twn[j].x * hi0 + twn[j].y * hr0);
            }
        }

        // ---- issue next frame's staging (into the OTHER buffer) ----
        if (it < FPW) stage(t + 1, c ^ 1);

        // ---- exchange region overlays the consumed staging buffer st[c].
        // Wave-ordered DS ops guarantee pack's reads precede these writes.
        float2* ex2 = (float2*)&st[c][0][0];   // 4128 B region, 8B-aligned

        // ---- stage A: IDFT8 over the 64s digit, twiddle w64^(k1*m0) ----
        idft8(zr8, zi8);
        {
            float tr = wA.x, ti = wA.y;
            #pragma unroll
            for (int m0 = 1; m0 < 8; ++m0) {
                cmul(zr8[m0], zi8[m0], tr, ti);
                cmul(tr, ti, wA.x, wA.y);
            }
        }
        // ---- exchange 1 (wave-internal, XOR swizzle, no barrier) ----
        #pragma unroll
        for (int m0 = 0; m0 < 8; ++m0)
            ex2[64 * m0 + 8 * ((k1 ^ m0) & 7) + k2] = make_float2(zr8[m0], zi8[m0]);
        #pragma unroll
        for (int kk = 0; kk < 8; ++kk) {
            const float2 v = ex2[64 * k1 + 8 * ((kk ^ k1) & 7) + k2];
            zr8[kk] = v.x; zi8[kk] = v.y;
        }

        // ---- stage B: IDFT8 over the 8s digit, twiddle w512^(k2*(m0B+8*m1)) ----
        idft8(zr8, zi8);
        {
            float tr = wB0.x, ti = wB0.y;
            #pragma unroll
            for (int m1 = 0; m1 < 8; ++m1) {
                cmul(zr8[m1], zi8[m1], tr, ti);
                cmul(tr, ti, wBs.x, wBs.y);
            }
        }
        // ---- exchange 2 (wave-internal) ----
        #pragma unroll
        for (int m1 = 0; m1 < 8; ++m1)
            ex2[64 * k2 + 8 * ((m1 ^ k2) & 7) + k1] = make_float2(zr8[m1], zi8[m1]);
        #pragma unroll
        for (int kk = 0; kk < 8; ++kk) {
            const float2 v = ex2[64 * kk + 8 * ((k1 ^ kk) & 7) + k2];
            zr8[kk] = v.x; zi8[kk] = v.y;
        }

        // ---- stage C: IDFT8 over the 1s digit -> z[u + 64*m2] ----
        idft8(zr8, zi8);

        // ---- overlap-add, carry in registers ----
        if (it >= 1) {
            float2* orow = (float2*)(out + ((size_t)b * NROWS + (size_t)t) * 512);
            #pragma unroll
            for (int m = 0; m < 4; ++m)
                orow[u + 64 * m] = make_float2(zr8[m] + cc[m].x, zi8[m] + cc[m].y);
        }
        #pragma unroll
        for (int m = 0; m < 4; ++m) cc[m] = make_float2(zr8[m + 4], zi8[m + 4]);
    }
}

extern "C" void kernel_launch(void* const* d_in, const int* in_sizes, int n_in,
                              void* d_out, int out_size, void* d_ws, size_t ws_size,
                              hipStream_t stream) {
    const float* re = (const float*)d_in[0];
    const float* im = (const float*)d_in[1];
    float* out = (float*)d_out;
    dim3 grid(CHAINS_PER_BATCH, BATCH);
    istft_kernel<<<grid, 64, 0, stream>>>(re, im, out);
}

// Round 17
// 44.639 us; speedup vs baseline: 1.1334x; 1.0263x over previous
//
#include <hip/hip_runtime.h>
#include <math.h>

#define NBINS 513
#define NROWS 4000
#define BATCH 8
#define FPW   16                         // output rows per chain (1 wave = 1 chain)
#define CHAINS_PER_BATCH (NROWS / FPW)   // 250

typedef const __attribute__((address_space(1))) void* gvp;
typedef __attribute__((address_space(3))) void* lvp;

__device__ __forceinline__ void cmul(float& ar, float& ai, float br, float bi) {
    const float t = ar * br - ai * bi;
    ai = ar * bi + ai * br;
    ar = t;
}

// In-place inverse DFT-8 (omega = e^{+2pi i/8}) on 8 complex register values.
__device__ __forceinline__ void idft8(float* xr, float* xi) {
    const float S = 0.70710678118654752440f;
    float er[4], ei[4], orr[4], oi[4];
    #pragma unroll
    for (int j = 0; j < 4; ++j) {
        er[j]  = xr[j] + xr[j+4];  ei[j] = xi[j] + xi[j+4];
        orr[j] = xr[j] - xr[j+4];  oi[j] = xi[j] - xi[j+4];
    }
    const float f1r = S * (orr[1] - oi[1]), f1i = S * (orr[1] + oi[1]);
    const float f2r = -oi[2],               f2i = orr[2];
    const float f3r = S * (-orr[3] - oi[3]), f3i = S * (orr[3] - oi[3]);
    {   // DFT4 (w4 = +i) over evens -> y0,y2,y4,y6
        const float eer = er[0]+er[2], eei = ei[0]+ei[2];
        const float eor = er[0]-er[2], eoi = ei[0]-ei[2];
        const float oer = er[1]+er[3], oei = ei[1]+ei[3];
        const float oor = er[1]-er[3], ooi = ei[1]-ei[3];
        xr[0] = eer + oer;  xi[0] = eei + oei;
        xr[2] = eor - ooi;  xi[2] = eoi + oor;
        xr[4] = eer - oer;  xi[4] = eei - oei;
        xr[6] = eor + ooi;  xi[6] = eoi - oor;
    }
    {   // DFT4 over odds*w8 -> y1,y3,y5,y7
        const float eer = orr[0]+f2r, eei = oi[0]+f2i;
        const float eor = orr[0]-f2r, eoi = oi[0]-f2i;
        const float oer = f1r+f3r,    oei = f1i+f3i;
        const float oor = f1r-f3r,    ooi = f1i-f3i;
        xr[1] = eer + oer;  xi[1] = eei + oei;
        xr[3] = eor - ooi;  xi[3] = eoi + oor;
        xr[5] = eer - oer;  xi[5] = eei - oei;
        xr[7] = eor + ooi;  xi[7] = eoi - oor;
    }
}

__global__ __launch_bounds__(64) void istft_kernel(
    const float* __restrict__ re, const float* __restrict__ im,
    float* __restrict__ out)
{
    __shared__ float  st[2][2][516];   // [buf][re/im][bin 0..512] staging
    __shared__ float2 ex2[512];        // exchange region

    const int u  = threadIdx.x;        // 0..63
    const int b  = blockIdx.y;
    const int t0 = blockIdx.x * FPW;

    const int k1 = u >> 3;
    const int k2 = u & 7;

    // ---- per-thread twiddles: 4 sincosf + recurrences (was 11 sincosf) ----
    const float w0 = 6.283185307179586476925f / 1024.0f;
    const float F  = 4.8828125e-4f;    // 0.5 (harness) * packed-irfft norm

    float2 twn[8];                     // F * i * w1024^(u+64j)  (pack rotation)
    {
        float s, c; sincosf(w0 * (float)u, &s, &c);
        twn[0] = make_float2(-F * s, F * c);
        // ratio e^{2pi i * 64/1024} = e^{i pi/8}: compile-time constants
        const float CR = 0.92387953251128675613f;   // cos(pi/8)
        const float CI = 0.38268343236508977173f;   // sin(pi/8)
        #pragma unroll
        for (int j = 1; j < 8; ++j) {
            twn[j] = twn[j - 1];
            cmul(twn[j].x, twn[j].y, CR, CI);
        }
    }
    float2 wA, wB0, wBs;               // stage twiddle recurrence bases
    {
        float s, c;
        sincosf(w0 * (float)(16 * k1), &s, &c);     wA  = make_float2(c, s);
        sincosf(w0 * (float)(2 * k2 * k1), &s, &c); wB0 = make_float2(c, s);
        sincosf(w0 * (float)(16 * k2), &s, &c);     wBs = make_float2(c, s);
    }

    float2 cc[4];                      // OLA carry (registers)
    #pragma unroll
    for (int m = 0; m < 4; ++m) cc[m] = make_float2(0.f, 0.f);

    const float* rebase = re + (size_t)b * NROWS * NBINS;
    const float* imbase = im + (size_t)b * NROWS * NBINS;

    // ---- async staging of one spectrum row into LDS (size=4: alignment-safe) ----
    auto stage = [&](int t, int buf) {
        const float* rp = rebase + (size_t)t * NBINS;
        const float* ip = imbase + (size_t)t * NBINS;
        #pragma unroll
        for (int jj = 0; jj < 8; ++jj)
            __builtin_amdgcn_global_load_lds((gvp)(rp + 64 * jj + u),
                                             (lvp)&st[buf][0][64 * jj], 4, 0, 0);
        __builtin_amdgcn_global_load_lds((gvp)(rp + 449 + u),
                                         (lvp)&st[buf][0][449], 4, 0, 0);
        #pragma unroll
        for (int jj = 0; jj < 8; ++jj)
            __builtin_amdgcn_global_load_lds((gvp)(ip + 64 * jj + u),
                                             (lvp)&st[buf][1][64 * jj], 4, 0, 0);
        __builtin_amdgcn_global_load_lds((gvp)(ip + 449 + u),
                                         (lvp)&st[buf][1][449], 4, 0, 0);
    };  // 18 vmcnt entries per frame

    // ---- prologue: stage the priming frame ----
    if (t0 == 0) {
        #pragma unroll
        for (int j = 0; j < 8; ++j) { st[0][0][u + 64 * j] = 0.f; st[0][1][u + 64 * j] = 0.f; }
        if (u == 0) { st[0][0][512] = 0.f; st[0][1][512] = 0.f; }
    } else {
        stage(t0 - 1, 0);
    }
    asm volatile("s_waitcnt vmcnt(0)" ::: "memory");

    for (int it = 0; it <= FPW; ++it) {
        const int t = t0 - 1 + it;
        const int c = it & 1;

        // ---- wait for frame t's staging: 18 loads must be done.
        // steady-state queue entering frame t = [stage(t):18][stores(t-1):4].
        if (it >= 2)      { asm volatile("s_waitcnt vmcnt(4)" ::: "memory"); }
        else if (it == 1) { asm volatile("s_waitcnt vmcnt(0)" ::: "memory"); }

        // ---- issue next frame's staging FIRST (buffer c^1 was consumed at
        //      frame t-1; wave-ordered DS makes the overwrite safe). Gives the
        //      DMA the whole pack+FFT (~3000cy) of latency cover.
        if (it < FPW) stage(t + 1, c ^ 1);

        // ---- pack from staged LDS row: z = F*e + twn*h  (k = u + 64j) ----
        float zr8[8], zi8[8];
        {
            const float* fr = st[c][0];
            const float* fi = st[c][1];
            #pragma unroll
            for (int j = 0; j < 8; ++j) {
                const int k = u + 64 * j;
                float xr = fr[k], xi = fi[k];
                float rc = fr[512 - k], ic = -fi[512 - k];
                if (k == 0) { xi = 0.f; ic = 0.f; }   // pocketfft c2r: Im ignored
                const float er0 = xr + rc, ei0 = xi + ic;
                const float hr0 = xr - rc, hi0 = xi - ic;
                zr8[j] = F * er0 + (twn[j].x * hr0 - twn[j].y * hi0);
                zi8[j] = F * ei0 + (twn[j].x * hi0 + twn[j].y * hr0);
            }
        }

        // ---- stage A: IDFT8 over the 64s digit, twiddle w64^(k1*m0) ----
        idft8(zr8, zi8);
        {
            float tr = wA.x, ti = wA.y;
            #pragma unroll
            for (int m0 = 1; m0 < 8; ++m0) {
                cmul(zr8[m0], zi8[m0], tr, ti);
                cmul(tr, ti, wA.x, wA.y);
            }
        }
        // ---- exchange 1 (wave-internal, XOR swizzle, no barrier) ----
        #pragma unroll
        for (int m0 = 0; m0 < 8; ++m0)
            ex2[64 * m0 + 8 * ((k1 ^ m0) & 7) + k2] = make_float2(zr8[m0], zi8[m0]);
        #pragma unroll
        for (int kk = 0; kk < 8; ++kk) {
            const float2 v = ex2[64 * k1 + 8 * ((kk ^ k1) & 7) + k2];
            zr8[kk] = v.x; zi8[kk] = v.y;
        }

        // ---- stage B: IDFT8 over the 8s digit, twiddle w512^(k2*(m0B+8*m1)) ----
        idft8(zr8, zi8);
        {
            float tr = wB0.x, ti = wB0.y;
            #pragma unroll
            for (int m1 = 0; m1 < 8; ++m1) {
                cmul(zr8[m1], zi8[m1], tr, ti);
                cmul(tr, ti, wBs.x, wBs.y);
            }
        }
        // ---- exchange 2 (wave-internal) ----
        #pragma unroll
        for (int m1 = 0; m1 < 8; ++m1)
            ex2[64 * k2 + 8 * ((m1 ^ k2) & 7) + k1] = make_float2(zr8[m1], zi8[m1]);
        #pragma unroll
        for (int kk = 0; kk < 8; ++kk) {
            const float2 v = ex2[64 * kk + 8 * ((k1 ^ kk) & 7) + k2];
            zr8[kk] = v.x; zi8[kk] = v.y;
        }

        // ---- stage C: IDFT8 over the 1s digit -> z[u + 64*m2] ----
        idft8(zr8, zi8);

        // ---- overlap-add, carry in registers ----
        if (it >= 1) {
            float2* orow = (float2*)(out + ((size_t)b * NROWS + (size_t)t) * 512);
            #pragma unroll
            for (int m = 0; m < 4; ++m)
                orow[u + 64 * m] = make_float2(zr8[m] + cc[m].x, zi8[m] + cc[m].y);
        }
        #pragma unroll
        for (int m = 0; m < 4; ++m) cc[m] = make_float2(zr8[m + 4], zi8[m + 4]);
    }
}

extern "C" void kernel_launch(void* const* d_in, const int* in_sizes, int n_in,
                              void* d_out, int out_size, void* d_ws, size_t ws_size,
                              hipStream_t stream) {
    const float* re = (const float*)d_in[0];
    const float* im = (const float*)d_in[1];
    float* out = (float*)d_out;
    dim3 grid(CHAINS_PER_BATCH, BATCH);
    istft_kernel<<<grid, 64, 0, stream>>>(re, im, out);
}